// Round 3
// baseline (149.598 us; speedup 1.0000x reference)
//
#include <hip/hip_runtime.h>
#include <math.h>

#define NN   1024
#define DIN_ 128
#define DD   32
#define EE   32768

// ---- workspace layout (floats) ----
// in_emb : NN*32
// lamp   : NN*32            (col0 = lam-1)
// sbuf   : EE*32            (stores es = exp(logit))
// -- zero region start --
// asum   : EE*32
// numb   : NN*32            (col0 = den)
// colsum : 32*16            (padded, one 64B line per column)
// count  : EE ints
// -- zero region end --
// slotmap: NN*NN ints       (-1 fill)
#define OFF_LAMP   (NN*DD)
#define OFF_SBUF   (2*NN*DD)
#define OFF_ZERO   (2*NN*DD + EE*DD)
#define OFF_NUMB   (OFF_ZERO + EE*DD)
#define OFF_COLS   (OFF_NUMB + NN*DD)
#define OFF_CNT    (OFF_COLS + 32*16)
#define OFF_SLOT   (OFF_CNT + EE)
#define ZERO_INT4  ((EE*DD + NN*DD + 32*16 + EE)/4)   // 278656
#define SLOT_INT4  ((NN*NN)/4)                        // 262144

__device__ __forceinline__ float artanh_f(float x){
    x = fminf(fmaxf(x, -1.f + 1e-7f), 1.f - 1e-7f);
    return 0.5f * (log1pf(x) - log1pf(-x));
}
__device__ __forceinline__ float arcosh_f(float x){
    x = fmaxf(x, 1.f + 1e-7f);
    return logf(x + sqrtf(x*x - 1.f));
}
__device__ __forceinline__ float rsum(float v){
#pragma unroll
    for (int off=16; off>0; off>>=1) v += __shfl_xor(v, off, 32);
    return v;
}
__device__ __forceinline__ float logmap0_l(float xv, int lane){
    float ss = rsum(lane>=1 ? xv*xv : 0.f);
    float yn = sqrtf(fmaxf(ss, 1e-15f));
    float x0 = __shfl(xv, 0, 32);
    float s  = arcosh_f(x0) / yn;
    return lane>=1 ? s*xv : 0.f;
}
__device__ __forceinline__ float expmap0_proj_l(float uv, int lane){
    float ss = rsum(lane>=1 ? uv*uv : 0.f);
    float xn = sqrtf(fmaxf(ss, 1e-15f));
    float sh = sinhf(xn)/xn;
    float o  = sh*uv;
    float ys = rsum(lane>=1 ? o*o : 0.f);
    float o0 = sqrtf(fmaxf(1.f+ys, 1e-7f));
    return lane==0 ? o0 : o;
}
__device__ __forceinline__ float mobius_add_proj_l(float xv, float yv, int lane){
    float u  = logmap0_l(yv, lane);
    float x1 = lane>=1 ? xv : 0.f;
    float ss = rsum(x1*x1);
    float xn = sqrtf(fmaxf(ss, 1e-15f));
    float alpha = rsum(x1*u) / xn;
    float x0 = __shfl(xv, 0, 32);
    float coef = alpha * (1.f - x0) / xn;
    float w  = lane>=1 ? u - coef*xv : 0.f;
    float ux = rsum(x1*w);
    float w0 = ux / fmaxf(x0, 1e-7f);
    float wsq = rsum(w*w);
    float nu = sqrtf(fmaxf(wsq - w0*w0, 1e-15f));
    float th = fmaxf(nu, 1e-15f);
    float ch = coshf(th), shq = sinhf(th)/th;
    float o  = ch*xv + shq*w;
    float ys = rsum(lane>=1 ? o*o : 0.f);
    float o0 = sqrtf(fmaxf(1.f+ys, 1e-7f));
    return lane==0 ? o0 : o;
}

// one fast fill replacing all runtime memsets
__global__ __launch_bounds__(256) void k_init(int4* __restrict__ zero_base,
                                              int4* __restrict__ slot_base){
    int tid = blockIdx.x*256 + threadIdx.x;
    int nthr = gridDim.x*256;
    int4 zz; zz.x=0; zz.y=0; zz.z=0; zz.w=0;
    int4 mm; mm.x=-1; mm.y=-1; mm.z=-1; mm.w=-1;
    for (int k=tid; k<ZERO_INT4; k+=nthr) zero_base[k]=zz;
    for (int k=tid; k<SLOT_INT4; k+=nthr) slot_base[k]=mm;
}

// per-node: in_emb = hyp_linear(x, Wd, bd); lamp row = [lam-1, lam*p_1..31]
__global__ __launch_bounds__(256) void k_node(const float* __restrict__ x,
        const float* __restrict__ Wd, const float* __restrict__ bd,
        float* __restrict__ in_emb, float* __restrict__ lamp){
    __shared__ float xs[8][128];
    __shared__ float Wd_s[32][129];
    int tid = threadIdx.x, lane = tid&31, grp = tid>>5;
    int node = blockIdx.x*8 + grp;
    for (int idx=tid; idx<32*128; idx+=256) Wd_s[idx>>7][idx&127] = Wd[idx];
#pragma unroll
    for (int r=0;r<4;++r) xs[grp][lane+32*r] = x[node*128 + lane + 32*r];
    __syncthreads();
    float ssp = 0.f;
#pragma unroll
    for (int r=0;r<4;++r){ int d=lane+32*r; float t=xs[grp][d]; if (d>=1) ssp += t*t; }
    float ss = rsum(ssp);
    float yn = sqrtf(fmaxf(ss, 1e-15f));
    float x0 = xs[grp][0];
    float scale = arcosh_f(x0)/yn;
    float acc = 0.f;
    for (int d=1; d<128; ++d) acc += Wd_s[lane][d]*xs[grp][d];
    float v = lane>=1 ? acc*scale : 0.f;
    float res = expmap0_proj_l(v, lane);
    float bt  = lane>=1 ? bd[lane] : 0.f;
    float hb  = expmap0_proj_l(bt, lane);
    float o   = mobius_add_proj_l(res, hb, lane);
    in_emb[node*32+lane] = o;
    float o0 = __shfl(o, 0, 32);
    float p  = lane>=1 ? o/(o0+1.f) : 0.f;
    float sq = rsum(p*p);
    float lam = 2.f/fmaxf(1.f-sq, 1e-15f);
    lamp[node*32+lane] = lane>=1 ? lam*p : lam-1.f;
}

// per-edge: es = exp(logit); claim slot; block-reduce colsum partials
__global__ __launch_bounds__(256) void k_edge_s(const int* __restrict__ edges,
        const float* __restrict__ Wa, const float* __restrict__ in_emb,
        float* __restrict__ sbuf, int* __restrict__ slotmap,
        float* __restrict__ colsum){
    __shared__ float Wa_s[32*65];
    __shared__ float cat_s[8][64];
    __shared__ float part[8][32];
    int tid = threadIdx.x, lane = tid&31, grp = tid>>5;
    int e = blockIdx.x*8 + grp;
    for (int idx=tid; idx<32*63; idx+=256){ int k=idx/63, c=idx-63*k; Wa_s[k*65+c]=Wa[idx]; }
    int i = edges[e], j = edges[EE+e];
    float A = in_emb[i*32+lane], B = in_emb[j*32+lane];
    float a0 = __shfl(A,0,32)+1.f, b0 = __shfl(B,0,32)+1.f;
    float pa = lane>=1 ? A/a0 : 0.f;
    float pb = lane>=1 ? B/b0 : 0.f;
    float sq = rsum(pa*pa + pb*pb);
    float dnm = fmaxf(1.f-sq, 1e-15f);
    float c0  = (1.f+sq)/dnm;
    float ya = 2.f*pa/dnm, yb = 2.f*pb/dnm;
    float ssy = rsum(ya*ya + yb*yb);
    float ynn = sqrtf(fmaxf(ssy, 1e-15f));
    float sc2 = arcosh_f(c0)/ynn;
    if (lane>=1){ cat_s[grp][lane-1]=ya; cat_s[grp][30+lane]=yb; }
    __syncthreads();
    float acc = 0.f;
    for (int t=0;t<62;++t) acc += Wa_s[lane*65+1+t]*cat_s[grp][t];
    float v = lane>=1 ? acc*sc2 : 0.f;
    float res = expmap0_proj_l(v, lane);
    float r   = logmap0_l(res, lane);
    r = r>=0.f ? r : 0.2f*r;
    float res2 = expmap0_proj_l(r, lane);
    float sv   = logmap0_l(res2, lane);
    float es   = lane>=1 ? expf(sv) : 0.f;    // softmax numerator (no max pass:
                                              // |logit| bounded, exp can't overflow)
    sbuf[e*32+lane] = es;
    if (lane==0) atomicMax(&slotmap[i*NN+j], e);
    part[grp][lane] = es;
    __syncthreads();
    if (grp==0){
        float s8 = 0.f;
#pragma unroll
        for (int g=0; g<8; ++g) s8 += part[g][lane];
        atomicAdd(&colsum[lane*16], s8);      // padded: one cache line per column
    }
}

// per-edge: softmax -> a = proj(expmap0([0,u])); accumulate per-cell sums
__global__ __launch_bounds__(256) void k_edge_a(const int* __restrict__ edges,
        const float* __restrict__ sbuf, const float* __restrict__ colsum,
        const int* __restrict__ slotmap,
        float* __restrict__ asum, int* __restrict__ count){
    int tid = threadIdx.x, lane = tid&31, grp = tid>>5;
    int e = blockIdx.x*8 + grp;
    float es = sbuf[e*32+lane];
    float u = lane>=1 ? es / colsum[lane*16] : 0.f;
    float a = expmap0_proj_l(u, lane);
    int i = edges[e], j = edges[EE+e];
    int slot = slotmap[i*NN+j];
    if (lane==0) atomicAdd(&count[slot], 1);
    atomicAdd(&asum[slot*32+lane], a);
}

// per unique cell (winner edge): att value, accumulate num/den rows
__global__ __launch_bounds__(256) void k_cell(const int* __restrict__ edges,
        const int* __restrict__ slotmap, const int* __restrict__ count,
        const float* __restrict__ asum, const float* __restrict__ in_emb,
        const float* __restrict__ lamp, float* __restrict__ numb){
    int tid = threadIdx.x, lane = tid&31, grp = tid>>5;
    int e = blockIdx.x*8 + grp;
    int i = edges[e], j = edges[EE+e];
    if (slotmap[i*NN+j] != e) return;
    float m  = (float)count[e];
    float ac = asum[e*32+lane];
    float w  = in_emb[j*32+lane];
    float ad = __shfl(ac,0,32)+1.f;
    float wd = m*__shfl(w,0,32)+1.f;
    float pa_ = lane>=1 ? ac/ad : 0.f;
    float pw  = lane>=1 ? m*w/wd : 0.f;
    float dot = rsum(pa_*pw);
    float wns = rsum(pw*pw);
    float wn  = sqrtf(fmaxf(wns, 1e-15f));
    float att = tanhf(dot/wn * artanh_f(wn));
    atomicAdd(&numb[i*32+lane], att*lamp[j*32+lane]);
}

// per-node epilogue
__global__ __launch_bounds__(256) void k_out(const float* __restrict__ numb,
        const float* __restrict__ Wo, const float* __restrict__ bo,
        float* __restrict__ out){
    __shared__ float Wo_s[32][33];
    int tid = threadIdx.x, lane = tid&31, grp = tid>>5;
    int i = blockIdx.x*8 + grp;
    for (int idx=tid; idx<1024; idx+=256) Wo_s[idx>>5][idx&31] = Wo[idx];
    __syncthreads();
    float nb = numb[i*32+lane];
    float dn = __shfl(nb, 0, 32);
    if (fabsf(dn) < 1e-10f) dn = 1e-10f;
    float g = lane>=1 ? nb/dn : 0.f;
    float gss = rsum(g*g);
    float gn = sqrtf(fmaxf(gss, 1e-15f));
    float scl = tanhf(0.5f*artanh_f(gn))/gn;
    g *= scl;
    float sq = rsum(g*g);
    float dnm = fmaxf(1.f-sq, 1e-15f);
    float h = lane==0 ? (1.f+sq)/dnm : 2.f*g/dnm;
    float r = logmap0_l(h, lane);
    float acc = 0.f;
#pragma unroll
    for (int d=1; d<32; ++d){ float rb = __shfl(r, d, 32); acc += Wo_s[lane][d]*rb; }
    float v = lane>=1 ? acc : 0.f;
    float res = expmap0_proj_l(v, lane);
    float bt  = lane>=1 ? bo[lane] : 0.f;
    float hb  = expmap0_proj_l(bt, lane);
    float o   = mobius_add_proj_l(res, hb, lane);
    out[i*32+lane] = o;
}

extern "C" void kernel_launch(void* const* d_in, const int* in_sizes, int n_in,
                              void* d_out, int out_size, void* d_ws, size_t ws_size,
                              hipStream_t stream) {
    const float* x  = (const float*)d_in[0];
    const int* edges = (const int*)d_in[1];
    const float* Wd = (const float*)d_in[2];
    const float* bd = (const float*)d_in[3];
    const float* Wa = (const float*)d_in[4];
    const float* Wo = (const float*)d_in[5];
    const float* bo = (const float*)d_in[6];
    float* out = (float*)d_out;

    float* f       = (float*)d_ws;
    float* in_emb  = f;
    float* lamp    = f + OFF_LAMP;
    float* sbuf    = f + OFF_SBUF;
    float* asum    = f + OFF_ZERO;
    float* numb    = f + OFF_NUMB;
    float* colsum  = f + OFF_COLS;
    int*   count   = (int*)(f + OFF_CNT);
    int*   slotmap = (int*)(f + OFF_SLOT);

    k_init<<<1024, 256, 0, stream>>>((int4*)(f + OFF_ZERO), (int4*)slotmap);
    k_node<<<NN/8, 256, 0, stream>>>(x, Wd, bd, in_emb, lamp);
    k_edge_s<<<EE/8, 256, 0, stream>>>(edges, Wa, in_emb, sbuf, slotmap, colsum);
    k_edge_a<<<EE/8, 256, 0, stream>>>(edges, sbuf, colsum, slotmap, asum, count);
    k_cell<<<EE/8, 256, 0, stream>>>(edges, slotmap, count, asum, in_emb, lamp, numb);
    k_out<<<NN/8, 256, 0, stream>>>(numb, Wo, bo, out);
}

// Round 4
// 68.912 us; speedup vs baseline: 2.1709x; 2.1709x over previous
//
#include <hip/hip_runtime.h>
#include <math.h>

#define NN   1024
#define DIN_ 128
#define DD   32
#define EE   32768

// ---- workspace layout (floats) ----
#define OFF_LAMP   (NN*DD)
#define OFF_SBUF   (2*NN*DD)
#define OFF_ZERO   (2*NN*DD + EE*DD)
#define OFF_NUMB   (OFF_ZERO + EE*DD)
#define OFF_COLS   (OFF_NUMB + NN*DD)
#define OFF_CNT    (OFF_COLS + 32*16)
#define OFF_SLOT   (OFF_CNT + EE)
#define ZERO_INT4  ((EE*DD + NN*DD + 32*16 + EE)/4)
#define SLOT_INT4  ((NN*NN)/4)

__device__ __forceinline__ float artanh_f(float x){
    x = fminf(fmaxf(x, -1.f + 1e-7f), 1.f - 1e-7f);
    return 0.5f * (log1pf(x) - log1pf(-x));
}
__device__ __forceinline__ float arcosh_f(float x){
    x = fmaxf(x, 1.f + 1e-7f);
    return logf(x + sqrtf(x*x - 1.f));
}
__device__ __forceinline__ float rsum(float v){
#pragma unroll
    for (int off=16; off>0; off>>=1) v += __shfl_xor(v, off, 32);
    return v;
}
__device__ __forceinline__ float logmap0_l(float xv, int lane){
    float ss = rsum(lane>=1 ? xv*xv : 0.f);
    float yn = sqrtf(fmaxf(ss, 1e-15f));
    float x0 = __shfl(xv, 0, 32);
    float s  = arcosh_f(x0) / yn;
    return lane>=1 ? s*xv : 0.f;
}
__device__ __forceinline__ float expmap0_proj_l(float uv, int lane){
    float ss = rsum(lane>=1 ? uv*uv : 0.f);
    float xn = sqrtf(fmaxf(ss, 1e-15f));
    float sh = sinhf(xn)/xn;
    float o  = sh*uv;
    float ys = rsum(lane>=1 ? o*o : 0.f);
    float o0 = sqrtf(fmaxf(1.f+ys, 1e-7f));
    return lane==0 ? o0 : o;
}
__device__ __forceinline__ float mobius_add_proj_l(float xv, float yv, int lane){
    float u  = logmap0_l(yv, lane);
    float x1 = lane>=1 ? xv : 0.f;
    float ss = rsum(x1*x1);
    float xn = sqrtf(fmaxf(ss, 1e-15f));
    float alpha = rsum(x1*u) / xn;
    float x0 = __shfl(xv, 0, 32);
    float coef = alpha * (1.f - x0) / xn;
    float w  = lane>=1 ? u - coef*xv : 0.f;
    float ux = rsum(x1*w);
    float w0 = ux / fmaxf(x0, 1e-7f);
    float wsq = rsum(w*w);
    float nu = sqrtf(fmaxf(wsq - w0*w0, 1e-15f));
    float th = fmaxf(nu, 1e-15f);
    float ch = coshf(th), shq = sinhf(th)/th;
    float o  = ch*xv + shq*w;
    float ys = rsum(lane>=1 ? o*o : 0.f);
    float o0 = sqrtf(fmaxf(1.f+ys, 1e-7f));
    return lane==0 ? o0 : o;
}

// one fast fill replacing all runtime memsets
__global__ __launch_bounds__(256) void k_init(int4* __restrict__ zero_base,
                                              int4* __restrict__ slot_base){
    int tid = blockIdx.x*256 + threadIdx.x;
    int nthr = gridDim.x*256;
    int4 zz; zz.x=0; zz.y=0; zz.z=0; zz.w=0;
    int4 mm; mm.x=-1; mm.y=-1; mm.z=-1; mm.w=-1;
    for (int k=tid; k<ZERO_INT4; k+=nthr) zero_base[k]=zz;
    for (int k=tid; k<SLOT_INT4; k+=nthr) slot_base[k]=mm;
}

// per-node: in_emb = hyp_linear(x, Wd, bd); lamp row = [lam-1, lam*p_1..31]
__global__ __launch_bounds__(256) void k_node(const float* __restrict__ x,
        const float* __restrict__ Wd, const float* __restrict__ bd,
        float* __restrict__ in_emb, float* __restrict__ lamp){
    __shared__ float xs[8][128];
    __shared__ float Wd_s[32][129];
    int tid = threadIdx.x, lane = tid&31, grp = tid>>5;
    int node = blockIdx.x*8 + grp;
    for (int idx=tid; idx<32*128; idx+=256) Wd_s[idx>>7][idx&127] = Wd[idx];
#pragma unroll
    for (int r=0;r<4;++r) xs[grp][lane+32*r] = x[node*128 + lane + 32*r];
    __syncthreads();
    float ssp = 0.f;
#pragma unroll
    for (int r=0;r<4;++r){ int d=lane+32*r; float t=xs[grp][d]; if (d>=1) ssp += t*t; }
    float ss = rsum(ssp);
    float yn = sqrtf(fmaxf(ss, 1e-15f));
    float x0 = xs[grp][0];
    float scale = arcosh_f(x0)/yn;
    float acc = 0.f;
    for (int d=1; d<128; ++d) acc += Wd_s[lane][d]*xs[grp][d];
    float v = lane>=1 ? acc*scale : 0.f;
    float res = expmap0_proj_l(v, lane);
    float bt  = lane>=1 ? bd[lane] : 0.f;
    float hb  = expmap0_proj_l(bt, lane);
    float o   = mobius_add_proj_l(res, hb, lane);
    in_emb[node*32+lane] = o;
    float o0 = __shfl(o, 0, 32);
    float p  = lane>=1 ? o/(o0+1.f) : 0.f;
    float sq = rsum(p*p);
    float lam = 2.f/fmaxf(1.f-sq, 1e-15f);
    lamp[node*32+lane] = lane>=1 ? lam*p : lam-1.f;
}

// per-edge: es = exp(logit); claim cell slot
__global__ __launch_bounds__(256) void k_edge_s(const int* __restrict__ edges,
        const float* __restrict__ Wa, const float* __restrict__ in_emb,
        float* __restrict__ sbuf, int* __restrict__ slotmap){
    __shared__ float Wa_s[32*65];
    __shared__ float cat_s[8][64];
    int tid = threadIdx.x, lane = tid&31, grp = tid>>5;
    int e = blockIdx.x*8 + grp;
    for (int idx=tid; idx<32*63; idx+=256){ int k=idx/63, c=idx-63*k; Wa_s[k*65+c]=Wa[idx]; }
    int i = edges[e], j = edges[EE+e];
    float A = in_emb[i*32+lane], B = in_emb[j*32+lane];
    float a0 = __shfl(A,0,32)+1.f, b0 = __shfl(B,0,32)+1.f;
    float pa = lane>=1 ? A/a0 : 0.f;
    float pb = lane>=1 ? B/b0 : 0.f;
    float sq = rsum(pa*pa + pb*pb);
    float dnm = fmaxf(1.f-sq, 1e-15f);
    float c0  = (1.f+sq)/dnm;
    float ya = 2.f*pa/dnm, yb = 2.f*pb/dnm;
    float ssy = rsum(ya*ya + yb*yb);
    float ynn = sqrtf(fmaxf(ssy, 1e-15f));
    float sc2 = arcosh_f(c0)/ynn;
    if (lane>=1){ cat_s[grp][lane-1]=ya; cat_s[grp][30+lane]=yb; }
    __syncthreads();
    float acc = 0.f;
    for (int t=0;t<62;++t) acc += Wa_s[lane*65+1+t]*cat_s[grp][t];
    float v = lane>=1 ? acc*sc2 : 0.f;
    float res = expmap0_proj_l(v, lane);
    float r   = logmap0_l(res, lane);
    r = r>=0.f ? r : 0.2f*r;
    float res2 = expmap0_proj_l(r, lane);
    float sv   = logmap0_l(res2, lane);
    float es   = lane>=1 ? expf(sv) : 0.f;    // softmax numerator (logits bounded,
                                              // exp can't overflow fp32)
    sbuf[e*32+lane] = es;
    if (lane==0) atomicMax(&slotmap[i*NN+j], e);
}

// hierarchical column sum: coalesced reads, low-contention atomics
__global__ __launch_bounds__(256) void k_colsum(const float* __restrict__ sbuf,
        float* __restrict__ colsum){
    __shared__ float part[8][32];
    int tid = threadIdx.x, lane = tid&31, grp = tid>>5;
    float acc = 0.f;
    int base = blockIdx.x*256 + grp*32;     // 128 blocks x 256 edges each
#pragma unroll
    for (int it=0; it<32; ++it) acc += sbuf[(base+it)*32 + lane];
    part[grp][lane] = acc;
    __syncthreads();
    if (grp==0){
        float s8 = 0.f;
#pragma unroll
        for (int g=0; g<8; ++g) s8 += part[g][lane];
        atomicAdd(&colsum[lane*16], s8);    // chain depth 128 per padded line
    }
}

// per-edge: softmax -> a = proj(expmap0([0,u])); accumulate per-cell sums
__global__ __launch_bounds__(256) void k_edge_a(const int* __restrict__ edges,
        const float* __restrict__ sbuf, const float* __restrict__ colsum,
        const int* __restrict__ slotmap,
        float* __restrict__ asum, int* __restrict__ count){
    int tid = threadIdx.x, lane = tid&31, grp = tid>>5;
    int e = blockIdx.x*8 + grp;
    float es = sbuf[e*32+lane];
    float u = lane>=1 ? es / colsum[lane*16] : 0.f;
    float a = expmap0_proj_l(u, lane);
    int i = edges[e], j = edges[EE+e];
    int slot = slotmap[i*NN+j];
    if (lane==0) atomicAdd(&count[slot], 1);
    atomicAdd(&asum[slot*32+lane], a);
}

// per unique cell (winner edge): att value, accumulate num/den rows
__global__ __launch_bounds__(256) void k_cell(const int* __restrict__ edges,
        const int* __restrict__ slotmap, const int* __restrict__ count,
        const float* __restrict__ asum, const float* __restrict__ in_emb,
        const float* __restrict__ lamp, float* __restrict__ numb){
    int tid = threadIdx.x, lane = tid&31, grp = tid>>5;
    int e = blockIdx.x*8 + grp;
    int i = edges[e], j = edges[EE+e];
    if (slotmap[i*NN+j] != e) return;
    float m  = (float)count[e];
    float ac = asum[e*32+lane];
    float w  = in_emb[j*32+lane];
    float ad = __shfl(ac,0,32)+1.f;
    float wd = m*__shfl(w,0,32)+1.f;
    float pa_ = lane>=1 ? ac/ad : 0.f;
    float pw  = lane>=1 ? m*w/wd : 0.f;
    float dot = rsum(pa_*pw);
    float wns = rsum(pw*pw);
    float wn  = sqrtf(fmaxf(wns, 1e-15f));
    float att = tanhf(dot/wn * artanh_f(wn));
    atomicAdd(&numb[i*32+lane], att*lamp[j*32+lane]);
}

// per-node epilogue
__global__ __launch_bounds__(256) void k_out(const float* __restrict__ numb,
        const float* __restrict__ Wo, const float* __restrict__ bo,
        float* __restrict__ out){
    __shared__ float Wo_s[32][33];
    int tid = threadIdx.x, lane = tid&31, grp = tid>>5;
    int i = blockIdx.x*8 + grp;
    for (int idx=tid; idx<1024; idx+=256) Wo_s[idx>>5][idx&31] = Wo[idx];
    __syncthreads();
    float nb = numb[i*32+lane];
    float dn = __shfl(nb, 0, 32);
    if (fabsf(dn) < 1e-10f) dn = 1e-10f;
    float g = lane>=1 ? nb/dn : 0.f;
    float gss = rsum(g*g);
    float gn = sqrtf(fmaxf(gss, 1e-15f));
    float scl = tanhf(0.5f*artanh_f(gn))/gn;
    g *= scl;
    float sq = rsum(g*g);
    float dnm = fmaxf(1.f-sq, 1e-15f);
    float h = lane==0 ? (1.f+sq)/dnm : 2.f*g/dnm;
    float r = logmap0_l(h, lane);
    float acc = 0.f;
#pragma unroll
    for (int d=1; d<32; ++d){ float rb = __shfl(r, d, 32); acc += Wo_s[lane][d]*rb; }
    float v = lane>=1 ? acc : 0.f;
    float res = expmap0_proj_l(v, lane);
    float bt  = lane>=1 ? bo[lane] : 0.f;
    float hb  = expmap0_proj_l(bt, lane);
    float o   = mobius_add_proj_l(res, hb, lane);
    out[i*32+lane] = o;
}

extern "C" void kernel_launch(void* const* d_in, const int* in_sizes, int n_in,
                              void* d_out, int out_size, void* d_ws, size_t ws_size,
                              hipStream_t stream) {
    const float* x  = (const float*)d_in[0];
    const int* edges = (const int*)d_in[1];
    const float* Wd = (const float*)d_in[2];
    const float* bd = (const float*)d_in[3];
    const float* Wa = (const float*)d_in[4];
    const float* Wo = (const float*)d_in[5];
    const float* bo = (const float*)d_in[6];
    float* out = (float*)d_out;

    float* f       = (float*)d_ws;
    float* in_emb  = f;
    float* lamp    = f + OFF_LAMP;
    float* sbuf    = f + OFF_SBUF;
    float* asum    = f + OFF_ZERO;
    float* numb    = f + OFF_NUMB;
    float* colsum  = f + OFF_COLS;
    int*   count   = (int*)(f + OFF_CNT);
    int*   slotmap = (int*)(f + OFF_SLOT);

    k_init<<<1024, 256, 0, stream>>>((int4*)(f + OFF_ZERO), (int4*)slotmap);
    k_node<<<NN/8, 256, 0, stream>>>(x, Wd, bd, in_emb, lamp);
    k_edge_s<<<EE/8, 256, 0, stream>>>(edges, Wa, in_emb, sbuf, slotmap);
    k_colsum<<<128, 256, 0, stream>>>(sbuf, colsum);
    k_edge_a<<<EE/8, 256, 0, stream>>>(edges, sbuf, colsum, slotmap, asum, count);
    k_cell<<<EE/8, 256, 0, stream>>>(edges, slotmap, count, asum, in_emb, lamp, numb);
    k_out<<<NN/8, 256, 0, stream>>>(numb, Wo, bo, out);
}